// Round 4
// baseline (53.468 us; speedup 1.0000x reference)
//
#include <hip/hip_runtime.h>

#define FRAME 160
#define ORDER 16
#define LPC_EPS 1e-8f
#define NF 32        // frames per block (8 per wave)
#define BS 256       // threads per block = 4 waves, each fully independent
#define SEG 20       // samples per part (8 parts per frame)
#define SX 164       // padded LDS row stride in floats (+4-float skew vs 160)
#define QPW 5        // float4 iterations per thread, per-wave staging (320 quads/wave)

// Round N: ZERO BARRIERS, with staging indexing FIXED to be truly wave-private.
// Round-3 failed because stage-in kept block-interleaved indexing (p=it*256+t):
// wave 0 staged frames {0,1,6,7,...} but computed frames 0..7 -> cross-wave
// race once __syncthreads was removed. Now wave w stages quads [320w,320w+320)
// == frames [8w,8w+8) exactly (64 consecutive float4 = 1024B contiguous per
// iteration -> per-wave coalescing unchanged), and computes those same frames.
// Verified row usage: window reads xs[fi][0..159], pre reads xs[fi][4..159],
// FIR writes xs[fi][sbase..sbase+19] -- all rows fi in [8w,8w+8).
// Same-wave LDS write->read ordering via s_waitcnt lgkmcnt(0) + sched_barrier
// (rule: hipcc can hoist ops past inline-asm waitcnt despite memory clobber).
// Levinson stays per-lane redundant (costs VALU issue only; round 0->1 showed
// 14us of issue == ~1us of duration). LDS 20,992B -> 7 blocks/CU; 28 resident
// waves, each an independent pipeline: VALU under LDS under VMEM.
__global__ __launch_bounds__(BS, 4) void lpc_fused(const float* __restrict__ x,
                                                   float* __restrict__ out) {
    __shared__ float xs[NF * SX];  // 20,992 B

    const int t = threadIdx.x;
    const int wv = t >> 6;       // wave id [0,4)
    const int ln = t & 63;       // lane
    const long long base = (long long)blockIdx.x * (NF * FRAME);

    // ---- stage in: wave w loads ITS OWN 8 frames (quads 320w..320w+319) ----
#pragma unroll
    for (int it = 0; it < QPW; ++it) {
        int p = wv * 320 + it * 64 + ln;  // quad index within block
        int f = p / 40;                   // 40 quads per frame; f in [8w, 8w+8)
        int off = (p - f * 40) * 4;
        float4 v = *(const float4*)(x + base + 4 * p);
        *(float4*)(&xs[f * SX + off]) = v;
    }
    // wave-private region: wait for OUR ds_writes only (no cross-wave sync)
    asm volatile("s_waitcnt lgkmcnt(0)" ::: "memory");
    __builtin_amdgcn_sched_barrier(0);

    const int fi = t >> 3;       // frame within block: wave w owns [8w, 8w+8)
    const int part = t & 7;      // n-range: [20*part, 20*part+20)
    const int sbase = SEG * part;

    // ---- window w[j] = x[sbase + j], j in [0,36), zero-padded past frame end ----
    float w[SEG + ORDER];
#pragma unroll
    for (int m = 0; m < (SEG + ORDER) / 4; ++m) {
        int idx = sbase + 4 * m;
        float4 v = make_float4(0.f, 0.f, 0.f, 0.f);
        if (idx < FRAME) v = *(const float4*)(&xs[fi * SX + idx]);
        w[4 * m + 0] = v.x; w[4 * m + 1] = v.y;
        w[4 * m + 2] = v.z; w[4 * m + 3] = v.w;
    }

    // ---- FIR look-back: pre[j] = x[sbase - 16 + j], zeros before frame start ----
    float pre[ORDER];
#pragma unroll
    for (int m = 0; m < ORDER / 4; ++m) {
        int idx = sbase - ORDER + 4 * m;
        float4 v = make_float4(0.f, 0.f, 0.f, 0.f);
        if (idx >= 0) v = *(const float4*)(&xs[fi * SX + idx]);
        pre[4 * m + 0] = v.x; pre[4 * m + 1] = v.y;
        pre[4 * m + 2] = v.z; pre[4 * m + 3] = v.w;
    }

    // ---- partial autocorrelation over 20 samples, all 17 lags ----
    float r[ORDER + 1];
#pragma unroll
    for (int k = 0; k <= ORDER; ++k) r[k] = 0.f;
#pragma unroll
    for (int n = 0; n < SEG; ++n) {
#pragma unroll
        for (int k = 0; k <= ORDER; ++k) {
            r[k] = fmaf(w[n], w[n + k], r[k]);
        }
    }
    // 8-lane butterfly: every lane of the group gets full-frame r[k]
#pragma unroll
    for (int k = 0; k <= ORDER; ++k) {
        r[k] += __shfl_xor(r[k], 1);
        r[k] += __shfl_xor(r[k], 2);
        r[k] += __shfl_xor(r[k], 4);
    }

    // ---- Levinson-Durbin: per-lane redundant (8x/frame). Costs VALU ISSUE
    //      only -- measured round 0->1: 14us issue == ~1us duration. Buys:
    //      no rbuf/abuf LDS traffic, no barriers, no cross-wave coupling. ----
    float a[ORDER + 1];
    a[0] = 1.f;
#pragma unroll
    for (int j = 1; j <= ORDER; ++j) a[j] = 0.f;
    float e = (r[0] != 0.f) ? r[0] : LPC_EPS;  // e >= EPS > 0 afterwards
#pragma unroll
    for (int i = 1; i <= ORDER; ++i) {
        float acc = r[i];
#pragma unroll
        for (int j = 1; j < i; ++j) acc -= a[j] * r[i - j];
        // e >= EPS always; v_rcp_f32 (~1 ulp) vs IEEE divide: rel err ~1e-7
        float k = acc * __builtin_amdgcn_rcpf(e);
        // a_new[j] = a[j] - k*a[i-j] for j=1..i-1, done as (j, i-j) pairs:
#pragma unroll
        for (int j = 1; 2 * j < i; ++j) {
            float aj = a[j], aij = a[i - j];
            a[j]     = aj  - k * aij;
            a[i - j] = aij - k * aj;
        }
        if ((i & 1) == 0) {
            int m = i >> 1;                 // self-paired middle element
            a[m] = a[m] - k * a[m];
        }
        a[i] = k;
        e = fmaxf(e * (1.f - k * k), LPC_EPS);
    }

    // ---- FIR: res[sbase+n] = sum_k a[k] * x[sbase+n-k], written in place.
    //      All of this wave's xs reads already completed (w/pre consumed). ----
#pragma unroll
    for (int m = 0; m < SEG / 4; ++m) {
        float o[4];
#pragma unroll
        for (int i = 0; i < 4; ++i) {
            int n = 4 * m + i;
            float s = 0.f;
#pragma unroll
            for (int k = 0; k <= ORDER; ++k) {
                int j = n - k;                       // compile-time
                float xv = (j >= 0) ? w[j] : pre[ORDER + j];
                s = fmaf(a[k], xv, s);
            }
            o[i] = s;
        }
        *(float4*)(&xs[fi * SX + sbase + 4 * m]) = make_float4(o[0], o[1], o[2], o[3]);
    }
    // wave-private region: wait for OUR FIR ds_writes, then read back
    asm volatile("s_waitcnt lgkmcnt(0)" ::: "memory");
    __builtin_amdgcn_sched_barrier(0);

    // ---- stage out: wave w stores ITS OWN 8 frames, per-wave coalesced ----
#pragma unroll
    for (int it = 0; it < QPW; ++it) {
        int p = wv * 320 + it * 64 + ln;
        int f = p / 40;
        int off = (p - f * 40) * 4;
        float4 v = *(const float4*)(&xs[f * SX + off]);
        *(float4*)(out + base + 4 * p) = v;
    }
}

extern "C" void kernel_launch(void* const* d_in, const int* in_sizes, int n_in,
                              void* d_out, int out_size, void* d_ws, size_t ws_size,
                              hipStream_t stream) {
    const float* x = (const float*)d_in[0];
    float* out = (float*)d_out;
    int total = in_sizes[0];                 // 20,480,000 = 128,000 frames
    int n_frames = total / FRAME;
    int n_blocks = n_frames / NF;            // 4000 (exact for this problem shape)
    lpc_fused<<<n_blocks, BS, 0, stream>>>(x, out);
}

// Round 5
// 52.895 us; speedup vs baseline: 1.0108x; 1.0108x over previous
//
#include <hip/hip_runtime.h>

#define FRAME 160
#define ORDER 16
#define LPC_EPS 1e-8f
#define NF 32        // frames per tile
#define BS 256       // threads per block (4 waves); 8 threads per frame
#define SEG 20       // samples per part (8 parts per frame)
#define SX 164       // padded LDS row stride in floats (+4-float skew vs 160)
#define AB 20        // rbuf/abuf row stride in floats
#define QPB (NF * FRAME / 4 / BS)  // 5 float4 per thread per tile
#define TILE (NF * FRAME)          // 5120 floats per tile
#define T 2          // tiles per block (2-deep software pipeline)

// Round 5 = round-1 structure (the 39.75us best: barriers + lock-step phases,
// which round-4 proved are GOOD for L2/LLC locality) + T14 async prefetch:
// each block owns 2 consecutive tiles; tile t+1's global loads are issued
// right after tile t's stage-in barrier and stay in flight across the whole
// ~2000-cycle compute phase, consumed by ds_write at the next loop head.
// Round-4 lessons baked in: do NOT remove barriers (occupancy unchanged 37%,
// HBM traffic +65MB from de-clustered accesses); do NOT store strided
// (round-2: 4x transactions). Levinson centralized on wave 0 (round 0->1:
// redundant version wastes 14us of issue) with fast rcp.
__global__ __launch_bounds__(BS, 4) void lpc_fused(const float* __restrict__ x,
                                                   float* __restrict__ out) {
    __shared__ float xs[NF * SX];    // 20,992 B
    __shared__ float rbuf[NF * AB];  //  2,560 B
    __shared__ float abuf[NF * AB];  //  2,560 B

    const int t = threadIdx.x;
    const int fi = t >> 3;       // frame within tile [0,32)
    const int part = t & 7;      // n-range: [20*part, 20*part+20)
    const int sbase = SEG * part;

    const long long tile0 = (long long)blockIdx.x * T;

    // ---- prefetch tile 0 into registers (5 coalesced float4/thread) ----
    float4 pf[QPB];
#pragma unroll
    for (int it = 0; it < QPB; ++it) {
        int p = it * BS + t;
        pf[it] = *(const float4*)(x + tile0 * TILE + 4 * p);
    }

#pragma unroll
    for (int tt = 0; tt < T; ++tt) {
        const long long base = (tile0 + tt) * TILE;

        // ---- stage in: ds_write the prefetched registers ----
#pragma unroll
        for (int it = 0; it < QPB; ++it) {
            int p = it * BS + t;              // quad index within tile [0,1280)
            int f = p / 40;                   // 40 quads per frame
            int off = (p - f * 40) * 4;
            *(float4*)(&xs[f * SX + off]) = pf[it];
        }
        __syncthreads();

        // ---- issue tile t+1 loads NOW: in flight across the whole compute ----
        if (tt + 1 < T) {
#pragma unroll
            for (int it = 0; it < QPB; ++it) {
                int p = it * BS + t;
                pf[it] = *(const float4*)(x + base + TILE + 4 * p);
            }
        }

        // ---- window w[j] = x[sbase + j], j in [0,36), zero-padded past end ----
        float w[SEG + ORDER];
#pragma unroll
        for (int m = 0; m < (SEG + ORDER) / 4; ++m) {
            int idx = sbase + 4 * m;
            float4 v = make_float4(0.f, 0.f, 0.f, 0.f);
            if (idx < FRAME) v = *(const float4*)(&xs[fi * SX + idx]);
            w[4 * m + 0] = v.x; w[4 * m + 1] = v.y;
            w[4 * m + 2] = v.z; w[4 * m + 3] = v.w;
        }

        // ---- FIR look-back: pre[j] = x[sbase-16+j], zeros before frame start ----
        float pre[ORDER];
#pragma unroll
        for (int m = 0; m < ORDER / 4; ++m) {
            int idx = sbase - ORDER + 4 * m;
            float4 v = make_float4(0.f, 0.f, 0.f, 0.f);
            if (idx >= 0) v = *(const float4*)(&xs[fi * SX + idx]);
            pre[4 * m + 0] = v.x; pre[4 * m + 1] = v.y;
            pre[4 * m + 2] = v.z; pre[4 * m + 3] = v.w;
        }

        // ---- partial autocorrelation over 20 samples, all 17 lags ----
        float r[ORDER + 1];
#pragma unroll
        for (int k = 0; k <= ORDER; ++k) r[k] = 0.f;
#pragma unroll
        for (int n = 0; n < SEG; ++n) {
#pragma unroll
            for (int k = 0; k <= ORDER; ++k) {
                r[k] = fmaf(w[n], w[n + k], r[k]);
            }
        }
        // 8-lane butterfly: every lane of the group gets full-frame r[k]
#pragma unroll
        for (int k = 0; k <= ORDER; ++k) {
            r[k] += __shfl_xor(r[k], 1);
            r[k] += __shfl_xor(r[k], 2);
            r[k] += __shfl_xor(r[k], 4);
        }

        // ---- publish r[] once per frame (lane part==0) ----
        if (part == 0) {
#pragma unroll
            for (int m = 0; m < 4; ++m)
                *(float4*)(&rbuf[fi * AB + 4 * m]) =
                    make_float4(r[4 * m], r[4 * m + 1], r[4 * m + 2], r[4 * m + 3]);
            rbuf[fi * AB + 16] = r[16];
        }
        __syncthreads();

        // ---- Levinson-Durbin: one thread per frame (wave 0 only) ----
        if (t < NF) {
            float rr[ORDER + 1];
#pragma unroll
            for (int m = 0; m < 4; ++m) {
                float4 v = *(const float4*)(&rbuf[t * AB + 4 * m]);
                rr[4 * m + 0] = v.x; rr[4 * m + 1] = v.y;
                rr[4 * m + 2] = v.z; rr[4 * m + 3] = v.w;
            }
            rr[16] = rbuf[t * AB + 16];

            float a[ORDER + 1];
            a[0] = 1.f;
#pragma unroll
            for (int j = 1; j <= ORDER; ++j) a[j] = 0.f;
            float e = (rr[0] != 0.f) ? rr[0] : LPC_EPS;  // e >= EPS > 0 after
#pragma unroll
            for (int i = 1; i <= ORDER; ++i) {
                float acc = rr[i];
#pragma unroll
                for (int j = 1; j < i; ++j) acc -= a[j] * rr[i - j];
                // e >= EPS always; v_rcp_f32 rel err ~1e-7, fine vs threshold
                float k = acc * __builtin_amdgcn_rcpf(e);
#pragma unroll
                for (int j = 1; 2 * j < i; ++j) {
                    float aj = a[j], aij = a[i - j];
                    a[j]     = aj  - k * aij;
                    a[i - j] = aij - k * aj;
                }
                if ((i & 1) == 0) {
                    int m = i >> 1;                 // self-paired middle element
                    a[m] = a[m] - k * a[m];
                }
                a[i] = k;
                e = fmaxf(e * (1.f - k * k), LPC_EPS);
            }
#pragma unroll
            for (int m = 0; m < 4; ++m)
                *(float4*)(&abuf[t * AB + 4 * m]) =
                    make_float4(a[4 * m + 1], a[4 * m + 2], a[4 * m + 3], a[4 * m + 4]);
        }
        __syncthreads();  // abuf visible; all xs reads already done (pre-rbuf)

        // ---- read back a[] (same address across 8 lanes -> LDS broadcast) ----
        float a[ORDER + 1];
        a[0] = 1.f;
#pragma unroll
        for (int m = 0; m < 4; ++m) {
            float4 v = *(const float4*)(&abuf[fi * AB + 4 * m]);
            a[4 * m + 1] = v.x; a[4 * m + 2] = v.y;
            a[4 * m + 3] = v.z; a[4 * m + 4] = v.w;
        }

        // ---- FIR: res[sbase+n] = sum_k a[k]*x[sbase+n-k], written in place ----
#pragma unroll
        for (int m = 0; m < SEG / 4; ++m) {
            float o[4];
#pragma unroll
            for (int i = 0; i < 4; ++i) {
                int n = 4 * m + i;
                float s = 0.f;
#pragma unroll
                for (int k = 0; k <= ORDER; ++k) {
                    int j = n - k;                       // compile-time
                    float xv = (j >= 0) ? w[j] : pre[ORDER + j];
                    s = fmaf(a[k], xv, s);
                }
                o[i] = s;
            }
            *(float4*)(&xs[fi * SX + sbase + 4 * m]) =
                make_float4(o[0], o[1], o[2], o[3]);
        }
        __syncthreads();

        // ---- stage out: fully coalesced ----
#pragma unroll
        for (int it = 0; it < QPB; ++it) {
            int p = it * BS + t;
            int f = p / 40;
            int off = (p - f * 40) * 4;
            float4 v = *(const float4*)(&xs[f * SX + off]);
            *(float4*)(out + base + 4 * p) = v;
        }

        // xs reads done before next tile's ds_write overwrites them
        if (tt + 1 < T) __syncthreads();
    }
}

extern "C" void kernel_launch(void* const* d_in, const int* in_sizes, int n_in,
                              void* d_out, int out_size, void* d_ws, size_t ws_size,
                              hipStream_t stream) {
    const float* x = (const float*)d_in[0];
    float* out = (float*)d_out;
    int total = in_sizes[0];                 // 20,480,000 = 128,000 frames
    int n_frames = total / FRAME;
    int n_blocks = n_frames / NF / T;        // 2000 (exact for this shape)
    lpc_fused<<<n_blocks, BS, 0, stream>>>(x, out);
}

// Round 6
// 41.640 us; speedup vs baseline: 1.2840x; 1.2703x over previous
//
#include <hip/hip_runtime.h>

#define FRAME 160
#define ORDER 16
#define LPC_EPS 1e-8f
#define NF 32        // frames per block
#define BS 256       // threads per block (4 waves); 8 threads per frame
#define SEG 20       // samples per part (8 parts per frame)
#define SX 164       // padded LDS row stride in floats (+4-float skew vs 160)
#define QPB (NF * FRAME / 4 / BS)  // 5 float4 per thread stage-in/out

// Round 6 = r1 skeleton (39.75us best) with Levinson DISTRIBUTED per-wave:
// exec-masking saves no issue cycles, so running the recursion on all 64
// lanes of a wave costs the same ~310 wave-instructions as running it on 1.
// r1 centralized it on wave 0 (3 waves idle at a barrier) and paid 2 extra
// barriers + rbuf/abuf LDS round-trips to ferry r[]/a[]. Now: 17-shfl gather
// (lane L takes frame (L&7)'s r[], group-uniform after the butterfly), all 4
// waves run Levinson in parallel on their own SIMDs, 16-shfl scatter returns
// a[]. Deletes rbuf/abuf (LDS 26112->20992), both middle barriers, and the
// idle-wave stall. The two MEMORY-phase barriers stay: r4 proved lock-step
// load/store phases protect L2/L3 locality (zero-barrier: FETCH 44->64MB,
// +13us); r5 proved register prefetch across barriers is defeated by the
// compiler's vmcnt(0)-before-s_barrier and spills (+55MB write traffic).
__global__ __launch_bounds__(BS, 4) void lpc_fused(const float* __restrict__ x,
                                                   float* __restrict__ out) {
    __shared__ float xs[NF * SX];  // 20,992 B

    const int t = threadIdx.x;
    const int ln = t & 63;       // lane within wave
    const long long base = (long long)blockIdx.x * (NF * FRAME);

    // ---- stage in: 1280 consecutive float4, fully coalesced ----
#pragma unroll
    for (int it = 0; it < QPB; ++it) {
        int p = it * BS + t;              // quad index within block [0,1280)
        int f = p / 40;                   // 40 quads per frame
        int off = (p - f * 40) * 4;
        float4 v = *(const float4*)(x + base + 4 * p);
        *(float4*)(&xs[f * SX + off]) = v;
    }
    __syncthreads();

    const int fi = t >> 3;       // frame within block [0,32)
    const int part = t & 7;      // n-range: [20*part, 20*part+20)
    const int sbase = SEG * part;

    // ---- window w[j] = x[sbase + j], j in [0,36), zero-padded past frame end ----
    float w[SEG + ORDER];
#pragma unroll
    for (int m = 0; m < (SEG + ORDER) / 4; ++m) {
        int idx = sbase + 4 * m;
        float4 v = make_float4(0.f, 0.f, 0.f, 0.f);
        if (idx < FRAME) v = *(const float4*)(&xs[fi * SX + idx]);
        w[4 * m + 0] = v.x; w[4 * m + 1] = v.y;
        w[4 * m + 2] = v.z; w[4 * m + 3] = v.w;
    }

    // ---- FIR look-back: pre[j] = x[sbase - 16 + j], zeros before frame start ----
    float pre[ORDER];
#pragma unroll
    for (int m = 0; m < ORDER / 4; ++m) {
        int idx = sbase - ORDER + 4 * m;
        float4 v = make_float4(0.f, 0.f, 0.f, 0.f);
        if (idx >= 0) v = *(const float4*)(&xs[fi * SX + idx]);
        pre[4 * m + 0] = v.x; pre[4 * m + 1] = v.y;
        pre[4 * m + 2] = v.z; pre[4 * m + 3] = v.w;
    }

    // ---- partial autocorrelation over 20 samples, all 17 lags ----
    float r[ORDER + 1];
#pragma unroll
    for (int k = 0; k <= ORDER; ++k) r[k] = 0.f;
#pragma unroll
    for (int n = 0; n < SEG; ++n) {
#pragma unroll
        for (int k = 0; k <= ORDER; ++k) {
            r[k] = fmaf(w[n], w[n + k], r[k]);
        }
    }
    // 8-lane butterfly: every lane of the group gets full-frame r[k]
#pragma unroll
    for (int k = 0; k <= ORDER; ++k) {
        r[k] += __shfl_xor(r[k], 1);
        r[k] += __shfl_xor(r[k], 2);
        r[k] += __shfl_xor(r[k], 4);
    }

    // ---- gather: lane L adopts frame (L&7) of its wave. Source lane
    //      (L&7)*8 is group (L&7)'s lane 0, which holds that frame's full
    //      r[] after the butterfly. 8x lane-redundant, 1x issue cost. ----
    float rr[ORDER + 1];
#pragma unroll
    for (int k = 0; k <= ORDER; ++k)
        rr[k] = __shfl(r[k], (ln & 7) << 3);

    // ---- Levinson-Durbin on the adopted frame (all waves in parallel) ----
    float ao[ORDER + 1];
    ao[0] = 1.f;
#pragma unroll
    for (int j = 1; j <= ORDER; ++j) ao[j] = 0.f;
    float e = (rr[0] != 0.f) ? rr[0] : LPC_EPS;  // e >= EPS > 0 afterwards
#pragma unroll
    for (int i = 1; i <= ORDER; ++i) {
        float acc = rr[i];
#pragma unroll
        for (int j = 1; j < i; ++j) acc -= ao[j] * rr[i - j];
        // e >= EPS always; v_rcp_f32 (~1 ulp) vs IEEE divide: rel err ~1e-7
        float k = acc * __builtin_amdgcn_rcpf(e);
        // a_new[j] = a[j] - k*a[i-j] for j=1..i-1, done as (j, i-j) pairs:
#pragma unroll
        for (int j = 1; 2 * j < i; ++j) {
            float aj = ao[j], aij = ao[i - j];
            ao[j]     = aj  - k * aij;
            ao[i - j] = aij - k * aj;
        }
        if ((i & 1) == 0) {
            int m = i >> 1;                 // self-paired middle element
            ao[m] = ao[m] - k * ao[m];
        }
        ao[i] = k;
        e = fmaxf(e * (1.f - k * k), LPC_EPS);
    }

    // ---- scatter: lane ln needs a[] of its own frame (ln>>3), which lane
    //      s = ln>>3 computed (s&7 == s for s<8). Exact bit-copy via shfl. ----
    float a[ORDER + 1];
    a[0] = 1.f;
#pragma unroll
    for (int k = 1; k <= ORDER; ++k)
        a[k] = __shfl(ao[k], ln >> 3);

    // ---- FIR: res[sbase+n] = sum_k a[k] * x[sbase+n-k], written in place.
    //      All of this group's xs reads (w/pre) already consumed. ----
#pragma unroll
    for (int m = 0; m < SEG / 4; ++m) {
        float o[4];
#pragma unroll
        for (int i = 0; i < 4; ++i) {
            int n = 4 * m + i;
            float s = 0.f;
#pragma unroll
            for (int k = 0; k <= ORDER; ++k) {
                int j = n - k;                       // compile-time
                float xv = (j >= 0) ? w[j] : pre[ORDER + j];
                s = fmaf(a[k], xv, s);
            }
            o[i] = s;
        }
        *(float4*)(&xs[fi * SX + sbase + 4 * m]) = make_float4(o[0], o[1], o[2], o[3]);
    }
    __syncthreads();  // stage-out reads rows written by ALL waves

    // ---- stage out: fully coalesced ----
#pragma unroll
    for (int it = 0; it < QPB; ++it) {
        int p = it * BS + t;
        int f = p / 40;
        int off = (p - f * 40) * 4;
        float4 v = *(const float4*)(&xs[f * SX + off]);
        *(float4*)(out + base + 4 * p) = v;
    }
}

extern "C" void kernel_launch(void* const* d_in, const int* in_sizes, int n_in,
                              void* d_out, int out_size, void* d_ws, size_t ws_size,
                              hipStream_t stream) {
    const float* x = (const float*)d_in[0];
    float* out = (float*)d_out;
    int total = in_sizes[0];                 // 20,480,000 = 128,000 frames
    int n_frames = total / FRAME;
    int n_blocks = n_frames / NF;            // 4000 (exact for this problem shape)
    lpc_fused<<<n_blocks, BS, 0, stream>>>(x, out);
}